// Round 1
// baseline (337.190 us; speedup 1.0000x reference)
//
#include <hip/hip_runtime.h>

#define HW   (256*256)        // 65536
#define VOL  (64*HW)          // 4194304 per batch volume
#define NTOT (4ull*VOL)
#define C1v  1e-4f
#define C2v  9e-4f
#define EPSv 1e-8f

// ws layout:
// [0   .. 43]    : w[11] float (1D separable weights)
// [64  .. 8255]  : partials[1024] double
// [8448 .. +5*VOL*4] : 5 field volumes (per-batch, reused across batches)

__global__ void init_weights(const float* __restrict__ k3, float* __restrict__ w) {
    int i = threadIdx.x;
    if (i < 11) {
        float s = 0.f;
        for (int t = 0; t < 121; ++t) s += k3[i * 121 + t];
        w[i] = s;   // = g[i]/sum(g) up to fp noise
    }
}

// Pass 1: separable W-conv then H-conv of 5 fields (x, y, x^2, y^2, xy) for one d-slice tile.
__global__ __launch_bounds__(256) void blur_hw(
    const float* __restrict__ x, const float* __restrict__ y,
    const float* __restrict__ w11, float* __restrict__ fields, int b)
{
    __shared__ float xs[26][74];
    __shared__ float ys[26][74];
    __shared__ float tf[5][26][64];

    const int d   = blockIdx.z;
    const int h0  = blockIdx.y * 16;
    const int w0  = blockIdx.x * 64;
    const int tid = threadIdx.x;

    float wl[11];
#pragma unroll
    for (int t = 0; t < 11; ++t) wl[t] = w11[t];

    const float* xb = x + (size_t)b * VOL + (size_t)d * HW;
    const float* yb = y + (size_t)b * VOL + (size_t)d * HW;

    // load halo tile 26 x 74 (zero-padded)
    for (int p = tid; p < 26 * 74; p += 256) {
        int r = p / 74, c = p % 74;
        int gh = h0 - 5 + r, gw = w0 - 5 + c;
        float xv = 0.f, yv = 0.f;
        if ((unsigned)gh < 256u && (unsigned)gw < 256u) {
            xv = xb[gh * 256 + gw];
            yv = yb[gh * 256 + gw];
        }
        xs[r][c] = xv;
        ys[r][c] = yv;
    }
    __syncthreads();

    // W-conv: 26 x 64 points, 5 fields computed on the fly from x,y
    for (int p = tid; p < 26 * 64; p += 256) {
        int r = p >> 6, c = p & 63;
        float aX = 0, aY = 0, aXX = 0, aYY = 0, aXY = 0;
#pragma unroll
        for (int k = 0; k < 11; ++k) {
            float xv = xs[r][c + k], yv = ys[r][c + k], wk = wl[k];
            aX  += wk * xv;
            aY  += wk * yv;
            aXX += wk * xv * xv;
            aYY += wk * yv * yv;
            aXY += wk * xv * yv;
        }
        tf[0][r][c] = aX;  tf[1][r][c] = aY;
        tf[2][r][c] = aXX; tf[3][r][c] = aYY; tf[4][r][c] = aXY;
    }
    __syncthreads();

    // H-conv: 16 x 64 outputs, store 5 fields to global
    for (int p = tid; p < 16 * 64; p += 256) {
        int r = p >> 6, c = p & 63;
        float o[5];
#pragma unroll
        for (int f = 0; f < 5; ++f) {
            float a = 0.f;
#pragma unroll
            for (int j = 0; j < 11; ++j) a += wl[j] * tf[f][r + j][c];
            o[f] = a;
        }
        size_t oi = (size_t)d * HW + (size_t)(h0 + r) * 256 + (w0 + c);
#pragma unroll
        for (int f = 0; f < 5; ++f) fields[(size_t)f * VOL + oi] = o[f];
    }
}

// Pass 2: D-conv (rolling register buffer) + SSIM map + block reduction.
__global__ __launch_bounds__(256) void dconv_ssim(
    const float* __restrict__ fields, const float* __restrict__ w11,
    double* __restrict__ partials, int b)
{
    const int col = blockIdx.x * 256 + threadIdx.x;  // 0..65535 within slice

    float wl[11];
#pragma unroll
    for (int t = 0; t < 11; ++t) wl[t] = w11[t];

    const float* fX  = fields;
    const float* fY  = fields + (size_t)VOL;
    const float* fXX = fields + 2 * (size_t)VOL;
    const float* fYY = fields + 3 * (size_t)VOL;
    const float* fXY = fields + 4 * (size_t)VOL;

    float bX[11], bY[11], bXX[11], bYY[11], bXY[11];
#pragma unroll
    for (int t = 0; t < 11; ++t) { bX[t] = 0; bY[t] = 0; bXX[t] = 0; bYY[t] = 0; bXY[t] = 0; }

    float acc = 0.f;
#pragma unroll
    for (int s = 0; s < 69; ++s) {
        const int slot = s % 11;                 // compile-time (full unroll)
        float vX = 0, vY = 0, vXX = 0, vYY = 0, vXY = 0;
        if (s < 64) {
            size_t idx = (size_t)s * HW + col;
            vX = fX[idx]; vY = fY[idx]; vXX = fXX[idx]; vYY = fYY[idx]; vXY = fXY[idx];
        }
        bX[slot] = vX; bY[slot] = vY; bXX[slot] = vXX; bYY[slot] = vYY; bXY[slot] = vXY;

        if (s >= 5) {
            float mX = 0, mY = 0, cXX = 0, cYY = 0, cXY = 0;
#pragma unroll
            for (int t = 0; t < 11; ++t) {
                const int j = (s + 1 + t) % 11;  // compile-time
                float wt = wl[t];
                mX  += wt * bX[j];
                mY  += wt * bY[j];
                cXX += wt * bXX[j];
                cYY += wt * bYY[j];
                cXY += wt * bXY[j];
            }
            float mx2 = mX * mX, my2 = mY * mY, mxy = mX * mY;
            float sx2 = cXX - mx2, sy2 = cYY - my2, sxy = cXY - mxy;
            float num = (2.f * mxy + C1v) * (2.f * sxy + C2v);
            float den = (mx2 + my2 + C1v) * (sx2 + sy2 + C2v);
            acc += num / (den + EPSv);
        }
    }

    // reduce 256 threads -> one partial per block (deterministic)
    for (int off = 32; off; off >>= 1) acc += __shfl_down(acc, off, 64);
    __shared__ float wsum[4];
    int lane = threadIdx.x & 63, wid = threadIdx.x >> 6;
    if (lane == 0) wsum[wid] = acc;
    __syncthreads();
    if (threadIdx.x == 0) {
        float s = wsum[0] + wsum[1] + wsum[2] + wsum[3];
        partials[b * 256 + blockIdx.x] = (double)s;
    }
}

__global__ void finalize(const double* __restrict__ partials, float* __restrict__ out) {
    __shared__ double sh[256];
    double s = 0.0;
    for (int i = threadIdx.x; i < 1024; i += 256) s += partials[i];
    sh[threadIdx.x] = s;
    __syncthreads();
    for (int stride = 128; stride; stride >>= 1) {
        if (threadIdx.x < stride) sh[threadIdx.x] += sh[threadIdx.x + stride];
        __syncthreads();
    }
    if (threadIdx.x == 0) out[0] = 1.0f - (float)(sh[0] / (double)NTOT);
}

extern "C" void kernel_launch(void* const* d_in, const int* in_sizes, int n_in,
                              void* d_out, int out_size, void* d_ws, size_t ws_size,
                              hipStream_t stream) {
    const float* x  = (const float*)d_in[0];
    const float* y  = (const float*)d_in[1];
    const float* k3 = (const float*)d_in[2];
    float* out = (float*)d_out;

    char* ws = (char*)d_ws;
    float*  w11      = (float*)ws;
    double* partials = (double*)(ws + 64);
    float*  fields   = (float*)(ws + 8448);

    init_weights<<<1, 64, 0, stream>>>(k3, w11);

    for (int b = 0; b < 4; ++b) {
        dim3 g1(4, 16, 64);  // W/64, H/16, D
        blur_hw<<<g1, 256, 0, stream>>>(x, y, w11, fields, b);
        dconv_ssim<<<256, 256, 0, stream>>>(fields, w11, partials, b);
    }

    finalize<<<1, 256, 0, stream>>>(partials, out);
}